// Round 11
// baseline (475.287 us; speedup 1.0000x reference)
//
#include <hip/hip_runtime.h>
#include <hip/hip_fp8.h>

typedef __bf16 bf16_t;
typedef __bf16 bf16x8 __attribute__((ext_vector_type(8)));
typedef float floatx16 __attribute__((ext_vector_type(16)));
typedef int intx8 __attribute__((ext_vector_type(8)));
typedef unsigned long long u64;

#define B_ 16
#define N_ 4096
#define K_ 32

// ws layout (bytes):
//   idx   u16 [16][4096][32]         @ 0        (4194304)
//   g_enc u32 [16][1024]             @ 4194304  (65536)
//   w3f8  fp8 lane-contig [131072]   @ 4259840  (131072)   (= w3 * 16)
//   w2sw  bf16 frag-major [8192]     @ 4390912  (16384)    (K-axis permuted)
//   tmat  f32 [16][9]                @ 4407296  (576)
//   f1buf f32 [16][512]              @ 4407872  (32768)

__device__ __forceinline__ unsigned enc_f(float f) {
    unsigned u = __float_as_uint(f);
    return (u & 0x80000000u) ? ~u : (u | 0x80000000u);
}
__device__ __forceinline__ float dec_f(unsigned e) {
    return __uint_as_float((e & 0x80000000u) ? (e & 0x7fffffffu) : ~e);
}

__device__ __forceinline__ float max3f(float a, float b, float c) {
    float d;
    asm("v_max3_f32 %0, %1, %2, %3" : "=v"(d) : "v"(a), "v"(b), "v"(c));
    return d;
}

// compare-exchange: a <- min, b <- max (v_min_u32 / v_max_u32)
__device__ __forceinline__ void ce(unsigned& a, unsigned& b) {
    const unsigned mn = a < b ? a : b;
    const unsigned mx = a < b ? b : a;
    a = mn; b = mx;
}

// Batcher odd-even sort of 8 (ascending), 19 CE
__device__ __forceinline__ void sort8(unsigned* k) {
    ce(k[0], k[1]); ce(k[2], k[3]); ce(k[4], k[5]); ce(k[6], k[7]);
    ce(k[0], k[2]); ce(k[1], k[3]); ce(k[4], k[6]); ce(k[5], k[7]);
    ce(k[1], k[2]); ce(k[5], k[6]);
    ce(k[0], k[4]); ce(k[1], k[5]); ce(k[2], k[6]); ce(k[3], k[7]);
    ce(k[2], k[4]); ce(k[3], k[5]);
    ce(k[1], k[2]); ce(k[3], k[4]); ce(k[5], k[6]);
}
// keep lowest 8 of r ∪ k (both ascending) -> r ascending
__device__ __forceinline__ void merge_top8(unsigned* r, const unsigned* k) {
    unsigned s[8];
    #pragma unroll
    for (int u = 0; u < 8; u++)
        s[u] = r[u] < k[7 - u] ? r[u] : k[7 - u];
    ce(s[0], s[4]); ce(s[1], s[5]); ce(s[2], s[6]); ce(s[3], s[7]);
    ce(s[0], s[2]); ce(s[1], s[3]); ce(s[4], s[6]); ce(s[5], s[7]);
    ce(s[0], s[1]); ce(s[2], s[3]); ce(s[4], s[5]); ce(s[6], s[7]);
    #pragma unroll
    for (int u = 0; u < 8; u++) r[u] = s[u];
}

// ---------------------------------------------------------------------------
// K1: kNN top-32 (round-10 tournament scan, measured ~equal-best).
// 16 thr/query x 256 cands; 16-cand tournament batches (sort8+sort8+
// merge_top8 pair, then fold into r); round-5 1-deep merges.
// grid 2048 x 512.  Side jobs: zero g_enc, build w3f8 (lane-contig) +
// w2sw (K-axis permuted: ic = ks*16 + 4*hi + 8*(jj>>2) + (jj&3)).
// ---------------------------------------------------------------------------
__global__ __launch_bounds__(512, 4) void knn_kernel(
    const float* __restrict__ x, const float* __restrict__ w3,
    const float* __restrict__ w2, unsigned short* __restrict__ idxb,
    unsigned* __restrict__ g_enc, unsigned char* __restrict__ w3f8,
    bf16_t* __restrict__ w2sw)
{
    __shared__ __align__(16) float4 cand[16 * 257];   // 65792 B
    unsigned* lists = (unsigned*)cand;                // reused after scan
    unsigned* m1 = ((unsigned*)cand) + 8192;          // merge scratch @ 32 KB
    const int tid = threadIdx.x;
    const int bid = blockIdx.x;  // 2048 blocks

    {
        const int g = bid * 512 + tid;
        if (g < 131072) {
            const int j  = g & 31;
            const int lI = (g >> 5) & 63;
            const int kq = (g >> 11) & 1;
            const int cb = g >> 12;
            const int mt2 = kq * 2 + (j >> 4), q = j & 15;
            const int lmI = lI & 31, hiI = lI >> 5;
            const int ch = mt2 * 32 + (q & 3) + 8 * (q >> 2) + 4 * hiI;
            __hip_fp8_e4m3 t(16.0f * w3[(cb * 32 + lmI) * 128 + ch]);
            w3f8[g] = t.__x;
        } else if (g < 139264) {
            const int o = g - 131072;
            const int f = o >> 9, r = o & 511, lI = r >> 3, jj = r & 7;
            const int ks = f & 3, nb = f >> 2, lmI = lI & 31, hiI = lI >> 5;
            const int ic = ks * 16 + 4 * hiI + 8 * (jj >> 2) + (jj & 3);
            w2sw[o] = (bf16_t)w2[(nb * 32 + lmI) * 64 + ic];
        } else if (g < 155648) {
            g_enc[g - 139264] = 0u;
        }
    }

    const int b  = bid >> 7;                    // 128 blocks per batch
    const int q  = tid >> 4;                    // local query 0..31
    const int n  = (bid & 127) * 32 + q;        // global query index
    const int t  = tid & 15;                    // candidate chunk
    const float* xb = x + b * 3 * N_;

    for (int j = tid; j < N_; j += 512) {
        float cx = xb[j], cy = xb[N_ + j], cz = xb[2 * N_ + j];
        cand[j + (j >> 8)] = make_float4(-2.f * cx, -2.f * cy, -2.f * cz,
                                         fmaf(cx, cx, fmaf(cy, cy, cz * cz)));
    }
    __syncthreads();

    const float xi0 = xb[n], xi1 = xb[N_ + n], xi2 = xb[2 * N_ + n];
    const float xisq1 = fmaf(xi0, xi0, fmaf(xi1, xi1, xi2 * xi2)) + 1.0f;

    unsigned r[8];
    #pragma unroll
    for (int s = 0; s < 8; s++) r[s] = 0x7F7FFFFFu;   // FLT_MAX sentinel

    const int j0 = t * 256;
    const int pb = t * 257;
    #pragma unroll 1
    for (int jb = 0; jb < 256; jb += 16) {
        unsigned ka[8], kb[8];
        #pragma unroll
        for (int u = 0; u < 8; u++) {
            const float4 c = cand[pb + jb + u];
            const float d = fmaf(c.z, xi2, fmaf(c.y, xi1, fmaf(c.x, xi0, c.w)));
            ka[u] = (__float_as_uint(d + xisq1) & 0xFFFFF000u)
                  | (unsigned)(j0 + jb + u);
        }
        #pragma unroll
        for (int u = 0; u < 8; u++) {
            const float4 c = cand[pb + jb + 8 + u];
            const float d = fmaf(c.z, xi2, fmaf(c.y, xi1, fmaf(c.x, xi0, c.w)));
            kb[u] = (__float_as_uint(d + xisq1) & 0xFFFFF000u)
                  | (unsigned)(j0 + jb + 8 + u);
        }
        sort8(ka);
        sort8(kb);
        merge_top8(ka, kb);      // ka = sorted lowest-8 of the 16
        merge_top8(r, ka);       // fold into running top-8
    }
    __syncthreads();

    #pragma unroll
    for (int k = 0; k < 8; k++) lists[tid * 9 + k] = r[k];
    __syncthreads();

    if (tid < 128) {
        const int q1 = tid >> 2, gi = tid & 3;
        const int base = (q1 * 16 + gi * 4) * 9;
        unsigned h0 = lists[base], h1 = lists[base + 9];
        unsigned h2 = lists[base + 18], h3 = lists[base + 27];
        int p0 = 0, p1 = 0, p2 = 0, p3 = 0;
        unsigned* outp = m1 + (q1 * 4 + gi) * 32;
        #pragma unroll 1
        for (int k = 0; k < 32; k++) {
            const unsigned m01 = h0 < h1 ? h0 : h1;
            const unsigned m23 = h2 < h3 ? h2 : h3;
            const unsigned v = m01 < m23 ? m01 : m23;
            outp[k] = v;
            if (m01 < m23) {
                if (h1 < h0) { p1++; h1 = p1 < 8 ? lists[base + 9 + p1] : 0xFFFFFFFFu; }
                else         { p0++; h0 = p0 < 8 ? lists[base + p0]     : 0xFFFFFFFFu; }
            } else {
                if (h3 < h2) { p3++; h3 = p3 < 8 ? lists[base + 27 + p3] : 0xFFFFFFFFu; }
                else         { p2++; h2 = p2 < 8 ? lists[base + 18 + p2] : 0xFFFFFFFFu; }
            }
        }
    }
    __syncthreads();

    if (tid < 32) {
        const unsigned* g0 = m1 + tid * 128;
        unsigned h0 = g0[0], h1 = g0[32], h2 = g0[64], h3 = g0[96];
        int p0 = 0, p1 = 0, p2 = 0, p3 = 0;
        const int nq = (bid & 127) * 32 + tid;
        unsigned short* op = idxb + ((size_t)(b * N_ + nq)) * K_;
        #pragma unroll 1
        for (int k = 0; k < K_; k++) {
            const unsigned m01 = h0 < h1 ? h0 : h1;
            const unsigned m23 = h2 < h3 ? h2 : h3;
            const unsigned v = m01 < m23 ? m01 : m23;
            op[k] = (unsigned short)(v & 0xFFFu);
            if (m01 < m23) {
                if (h1 < h0) { p1++; h1 = p1 < 32 ? g0[32 + p1] : 0xFFFFFFFFu; }
                else         { p0++; h0 = p0 < 32 ? g0[p0]      : 0xFFFFFFFFu; }
            } else {
                if (h3 < h2) { p3++; h3 = p3 < 32 ? g0[96 + p3] : 0xFFFFFFFFu; }
                else         { p2++; h2 = p2 < 32 ? g0[64 + p2] : 0xFFFFFFFFu; }
            }
        }
    }
}

// epilogue for one finished layer-3 chunk: max-reduce 32 values via v_max3
// chains and LDS atomicMax (both half-wave lanes hit the same slot).
__device__ __forceinline__ void chunk_epilogue(
    const floatx16& a0, const floatx16& a1, int cb, unsigned* gl, int lm)
{
    float c0 = fmaxf(a0[0], a1[0]);
    float c1 = fmaxf(a0[1], a1[1]);
    float c2 = fmaxf(a0[2], a1[2]);
    float c3 = fmaxf(a0[3], a1[3]);
    #pragma unroll
    for (int o = 4; o < 16; o += 4) {
        c0 = max3f(a0[o + 0], a1[o + 0], c0);
        c1 = max3f(a0[o + 1], a1[o + 1], c1);
        c2 = max3f(a0[o + 2], a1[o + 2], c2);
        c3 = max3f(a0[o + 3], a1[o + 3], c3);
    }
    const float m = max3f(c0, c1, fmaxf(c2, c3));
    atomicMax(&gl[cb * 32 + lm], enc_f(m));
}

// ---------------------------------------------------------------------------
// K2: fused edge MLP — round-5 verified body, UNCHANGED.  Launched as TWO
// half-batch dispatches (grid 4096 each, x/idxb/g_enc pointer-offset by 8
// batches) purely so knn_kernel (~195 us) surfaces in the rocprof top-5
// window: each half ~124 us.  b = blockIdx.x>>9 covers batches 0..7 within
// each dispatch.
// ---------------------------------------------------------------------------
__global__ __launch_bounds__(256, 3) void mlp_kernel(
    const float* __restrict__ x, const unsigned short* __restrict__ idxb,
    const float* __restrict__ w1, const float* __restrict__ b1,
    const float* __restrict__ b2,
    const bf16_t* __restrict__ w2sw, const unsigned char* __restrict__ w3f8,
    unsigned* __restrict__ g_enc)
{
    __shared__ unsigned gl[1024];                 // 4096 B
    __shared__ __align__(16) float4 w1l[64];      // 1024 B
    __shared__ __align__(16) float b2s[128];      // 512 B  (= 256*b2)

    const int tid = threadIdx.x;
    const int b   = blockIdx.x >> 9;          // 512 blocks per batch
    const int p0  = (blockIdx.x & 511) * 8;   // first point
    const float* xb = x + b * 3 * N_;

    const int wv = tid >> 6;
    const int l  = tid & 63;
    const int lm = l & 31;
    const int hi = l >> 5;

    for (int i = tid; i < 1024; i += 256) gl[i] = 0u;
    if (tid < 64)
        w1l[tid] = make_float4(w1[tid * 3], w1[tid * 3 + 1], w1[tid * 3 + 2], b1[tid]);
    else if (tid < 192)
        b2s[tid - 64] = 256.0f * b2[tid - 64];
    __syncthreads();

    const floatx16 zf = (floatx16)0.f;   // hoisted zero C-input

    const unsigned char* w3p = w3f8 + l * 32;
#define PREFETCH_W3(dst, c) do {                                              \
        dst[0] = *(const intx8*)(w3p + (c) * 4096);                           \
        dst[1] = *(const intx8*)(w3p + (c) * 4096 + 2048);                    \
    } while (0)

    intx8 bwA[2], bwB[2];
    PREFETCH_W3(bwA, 0);     // in flight during layers 1+2

    // ---- edge gathers ----
    float d0[2], d1[2], d2[2];
    #pragma unroll
    for (int nt2 = 0; nt2 < 2; nt2++) {
        const int pp = p0 + wv * 2 + nt2;                // wave-uniform point
        const int j  = idxb[((size_t)(b * N_ + pp)) * K_ + lm];
        d0[nt2] = xb[j]          - xb[pp];
        d1[nt2] = xb[N_ + j]     - xb[N_ + pp];
        d2[nt2] = xb[2 * N_ + j] - xb[2 * N_ + pp];
    }

    // ---- layer 1 via MFMA (K=4, bias in k=3) ----
    bf16x8 a1f[2];                       // A: (w1|b1) per 32-ch tile, hi=0 only
    #pragma unroll
    for (int tt = 0; tt < 2; tt++) {
        const float4 w = w1l[tt * 32 + lm];
        bf16x8 v = (bf16x8)(bf16_t)0.f;
        if (hi == 0) {
            v[0] = (bf16_t)w.x; v[1] = (bf16_t)w.y;
            v[2] = (bf16_t)w.z; v[3] = (bf16_t)w.w;
        }
        a1f[tt] = v;
    }

    bf16x8 b1h[2][4];   // [nt2][ks]; layer-2 B-frags
    #pragma unroll
    for (int nt2 = 0; nt2 < 2; nt2++) {
        bf16x8 bf = (bf16x8)(bf16_t)0.f;   // B: (d0,d1,d2,1), hi=0 only
        if (hi == 0) {
            bf[0] = (bf16_t)d0[nt2]; bf[1] = (bf16_t)d1[nt2];
            bf[2] = (bf16_t)d2[nt2]; bf[3] = (bf16_t)1.0f;
        }
        floatx16 hacc[2];
        hacc[0] = __builtin_amdgcn_mfma_f32_32x32x16_bf16(a1f[0], bf, zf, 0, 0, 0);
        hacc[1] = __builtin_amdgcn_mfma_f32_32x32x16_bf16(a1f[1], bf, zf, 0, 0, 0);
        #pragma unroll
        for (int ks = 0; ks < 4; ks++)
            #pragma unroll
            for (int jj = 0; jj < 8; jj++)
                b1h[nt2][ks][jj] = (bf16_t)fmaxf(
                    hacc[ks >> 1][(jj & 3) + 4 * (jj >> 2) + 8 * (ks & 1)], 0.f);
    }

    // ---- layer 2 (MFMA 32x32x16 bf16, transposed) + fused fp8 pack -> a3v ----
    intx8 a3v[2][2];   // [nt2 = edge m-tile][kq]; byte map matches w3f8
    #pragma unroll
    for (int mt2 = 0; mt2 < 4; mt2++) {          // channel tile (M side)
        floatx16 acc0 = (floatx16)0.f, acc1 = (floatx16)0.f;
        #pragma unroll
        for (int ks = 0; ks < 4; ks++) {
            const bf16x8 aw = *(const bf16x8*)&w2sw[((mt2 * 4 + ks) * 64 + l) * 8];
            acc0 = __builtin_amdgcn_mfma_f32_32x32x16_bf16(aw, b1h[0][ks], acc0, 0, 0, 0);
            acc1 = __builtin_amdgcn_mfma_f32_32x32x16_bf16(aw, b1h[1][ks], acc1, 0, 0, 0);
        }
        const int kq = mt2 >> 1, c0 = (mt2 & 1) * 4;
        #pragma unroll
        for (int i2 = 0; i2 < 4; i2++) {
            // channels mt2*32 + 8*i2 + 4*hi + {0..3}  (lane-uniform per hi)
            const float4 bb = *(const float4*)&b2s[mt2 * 32 + i2 * 8 + hi * 4];
            {
                const float v0 = fmaxf(fmaf(acc0[4 * i2 + 0], 256.f, bb.x), 0.f);
                const float v1 = fmaxf(fmaf(acc0[4 * i2 + 1], 256.f, bb.y), 0.f);
                const float v2 = fmaxf(fmaf(acc0[4 * i2 + 2], 256.f, bb.z), 0.f);
                const float v3 = fmaxf(fmaf(acc0[4 * i2 + 3], 256.f, bb.w), 0.f);
                int w = __builtin_amdgcn_cvt_pk_fp8_f32(v0, v1, 0, false);
                w = __builtin_amdgcn_cvt_pk_fp8_f32(v2, v3, w, true);
                a3v[0][kq][c0 + i2] = w;
            }
            {
                const float v0 = fmaxf(fmaf(acc1[4 * i2 + 0], 256.f, bb.x), 0.f);
                const float v1 = fmaxf(fmaf(acc1[4 * i2 + 1], 256.f, bb.y), 0.f);
                const float v2 = fmaxf(fmaf(acc1[4 * i2 + 2], 256.f, bb.z), 0.f);
                const float v3 = fmaxf(fmaf(acc1[4 * i2 + 3], 256.f, bb.w), 0.f);
                int w = __builtin_amdgcn_cvt_pk_fp8_f32(v0, v1, 0, false);
                w = __builtin_amdgcn_cvt_pk_fp8_f32(v2, v3, w, true);
                a3v[1][kq][c0 + i2] = w;
            }
        }
    }

    // ---- layer 3: 32 chunks of 32 out-channels; scaled fp8 MFMA (K=64),
    //      pairwise double-pipeline: MFMA of chunk c || epilogue of c-1 ----
#define COMPUTE_W3(d0_, d1_, buf) do {                                        \
        __builtin_amdgcn_s_setprio(1);                                        \
        d0_ = __builtin_amdgcn_mfma_scale_f32_32x32x64_f8f6f4(                \
            a3v[0][0], buf[0], zf, 0, 0, 0, 0x7F7F7F7F, 0, 0x7F7F7F7F);       \
        d1_ = __builtin_amdgcn_mfma_scale_f32_32x32x64_f8f6f4(                \
            a3v[1][0], buf[0], zf, 0, 0, 0, 0x7F7F7F7F, 0, 0x7F7F7F7F);       \
        d0_ = __builtin_amdgcn_mfma_scale_f32_32x32x64_f8f6f4(                \
            a3v[0][1], buf[1], d0_, 0, 0, 0, 0x7F7F7F7F, 0, 0x7F7F7F7F);      \
        d1_ = __builtin_amdgcn_mfma_scale_f32_32x32x64_f8f6f4(                \
            a3v[1][1], buf[1], d1_, 0, 0, 0, 0x7F7F7F7F, 0, 0x7F7F7F7F);      \
        __builtin_amdgcn_s_setprio(0); } while (0)

    floatx16 pA0, pA1, pB0, pB1;

    PREFETCH_W3(bwB, 1);
    COMPUTE_W3(pA0, pA1, bwA);          // chunk 0

    #pragma unroll 1
    for (int cc = 0; cc < 15; cc++) {
        PREFETCH_W3(bwA, 2 * cc + 2);
        COMPUTE_W3(pB0, pB1, bwB);      // chunk 2cc+1
        chunk_epilogue(pA0, pA1, 2 * cc, gl, lm);
        PREFETCH_W3(bwB, 2 * cc + 3);
        COMPUTE_W3(pA0, pA1, bwA);      // chunk 2cc+2
        chunk_epilogue(pB0, pB1, 2 * cc + 1, gl, lm);
    }
    COMPUTE_W3(pB0, pB1, bwB);          // chunk 31
    chunk_epilogue(pA0, pA1, 30, gl, lm);
    chunk_epilogue(pB0, pB1, 31, gl, lm);

#undef PREFETCH_W3
#undef COMPUTE_W3

    __syncthreads();
    for (int i = tid; i < 1024; i += 256)
        atomicMax(&g_enc[b * 1024 + i], gl[i]);
}

// ---------------------------------------------------------------------------
// K3a: FC head layer 1, split across 128 blocks (8 per batch) so the 2 MB
// fw1 read spreads over 128 CUs.  4 threads/output, LDS reduce.
// ---------------------------------------------------------------------------
__global__ __launch_bounds__(256) void head1_kernel(
    const unsigned* __restrict__ g_enc, const float* __restrict__ b3,
    const float* __restrict__ fw1, const float* __restrict__ fb1,
    float* __restrict__ f1buf)
{
    __shared__ __align__(16) float g[1024];
    __shared__ float red[256];
    const int t = threadIdx.x;
    const int b = blockIdx.x >> 3;       // batch
    const int s = blockIdx.x & 7;        // output slice (64 outs)

    for (int i = t; i < 1024; i += 256)
        g[i] = fmaxf(fmaf(dec_f(g_enc[b * 1024 + i]), 2.44140625e-4f, b3[i]), 0.f);
    __syncthreads();

    const int o = s * 64 + (t & 63);
    const int quarter = t >> 6;
    const float4* wr = (const float4*)(fw1 + (size_t)o * 1024) + quarter * 64;
    const float4* gv = (const float4*)g + quarter * 64;
    float acc = 0.f;
    #pragma unroll 4
    for (int i = 0; i < 64; i++) {
        float4 a = wr[i], c = gv[i];
        acc = fmaf(a.x, c.x, acc); acc = fmaf(a.y, c.y, acc);
        acc = fmaf(a.z, c.z, acc); acc = fmaf(a.w, c.w, acc);
    }
    red[t] = acc;
    __syncthreads();
    if (t < 64) {
        const float v = red[t] + red[t + 64] + red[t + 128] + red[t + 192];
        f1buf[b * 512 + s * 64 + t] = fmaxf(v + fb1[s * 64 + t], 0.f);
    }
}

// ---------------------------------------------------------------------------
// K3b: FC head layers 2+3. grid 16 x 256.
// ---------------------------------------------------------------------------
__global__ __launch_bounds__(256) void head2_kernel(
    const float* __restrict__ f1buf,
    const float* __restrict__ fw2, const float* __restrict__ fb2,
    const float* __restrict__ fw3, const float* __restrict__ fb3,
    float* __restrict__ tmat)
{
    __shared__ __align__(16) float f1[512];
    __shared__ __align__(16) float f2[256];
    const int t = threadIdx.x, b = blockIdx.x;

    if (t < 128) ((float4*)f1)[t] = ((const float4*)(f1buf + b * 512))[t];
    __syncthreads();
    {
        const int o = t;
        const float4* wr = (const float4*)(fw2 + (size_t)o * 512);
        const float4* fv = (const float4*)f1;
        float acc = fb2[o];
        for (int i = 0; i < 128; i++) {
            float4 a = wr[i], c = fv[i];
            acc = fmaf(a.x, c.x, acc); acc = fmaf(a.y, c.y, acc);
            acc = fmaf(a.z, c.z, acc); acc = fmaf(a.w, c.w, acc);
        }
        f2[o] = fmaxf(acc, 0.f);
    }
    __syncthreads();
    if (t < 9) {
        const float4* wr = (const float4*)(fw3 + (size_t)t * 256);
        const float4* fv = (const float4*)f2;
        float acc = fb3[t];
        for (int i = 0; i < 64; i++) {
            float4 a = wr[i], c = fv[i];
            acc = fmaf(a.x, c.x, acc); acc = fmaf(a.y, c.y, acc);
            acc = fmaf(a.z, c.z, acc); acc = fmaf(a.w, c.w, acc);
        }
        if (t == 0 || t == 4 || t == 8) acc += 1.f;
        tmat[b * 9 + t] = acc;
    }
}

// ---------------------------------------------------------------------------
// K4: out[b][d][n] = sum_c x[b][c][n] * t[b][c][d].  grid 256 x 256.
// ---------------------------------------------------------------------------
__global__ __launch_bounds__(256) void out_kernel(
    const float* __restrict__ x, const float* __restrict__ tmat,
    float* __restrict__ out)
{
    const int gid = blockIdx.x * 256 + threadIdx.x;
    const int b = gid >> 12, n = gid & 4095;
    const float* T = tmat + b * 9;
    const float x0 = x[b * 12288 + n];
    const float x1 = x[b * 12288 + 4096 + n];
    const float x2 = x[b * 12288 + 8192 + n];
    #pragma unroll
    for (int d = 0; d < 3; d++)
        out[b * 12288 + d * 4096 + n] =
            fmaf(x2, T[6 + d], fmaf(x1, T[3 + d], x0 * T[d]));
}

extern "C" void kernel_launch(void* const* d_in, const int* in_sizes, int n_in,
                              void* d_out, int out_size, void* d_ws, size_t ws_size,
                              hipStream_t stream) {
    const float* x   = (const float*)d_in[0];
    const float* w1  = (const float*)d_in[1];
    const float* b1  = (const float*)d_in[2];
    const float* w2  = (const float*)d_in[3];
    const float* b2  = (const float*)d_in[4];
    const float* w3  = (const float*)d_in[5];
    const float* b3  = (const float*)d_in[6];
    const float* fw1 = (const float*)d_in[7];
    const float* fb1 = (const float*)d_in[8];
    const float* fw2 = (const float*)d_in[9];
    const float* fb2 = (const float*)d_in[10];
    const float* fw3 = (const float*)d_in[11];
    const float* fb3 = (const float*)d_in[12];
    float* out = (float*)d_out;

    char* ws = (char*)d_ws;
    unsigned short* idxb = (unsigned short*)ws;
    unsigned* g_enc = (unsigned*)(ws + 4194304);
    unsigned char* w3f8 = (unsigned char*)(ws + 4259840);
    bf16_t* w2sw = (bf16_t*)(ws + 4390912);
    float* tmat  = (float*)(ws + 4407296);
    float* f1buf = (float*)(ws + 4407872);

    knn_kernel<<<2048, 512, 0, stream>>>(x, w3, w2, idxb, g_enc, w3f8, w2sw);
    // mlp split into two half-batch dispatches (batches 0-7 / 8-15) so
    // knn_kernel surfaces in the rocprof top-5 window.
    mlp_kernel<<<4096, 256, 0, stream>>>(x, idxb, w1, b1, b2, w2sw, w3f8, g_enc);
    mlp_kernel<<<4096, 256, 0, stream>>>(x + 8 * 3 * N_, idxb + (size_t)8 * N_ * K_,
                                         w1, b1, b2, w2sw, w3f8, g_enc + 8 * 1024);
    head1_kernel<<<128, 256, 0, stream>>>(g_enc, b3, fw1, fb1, f1buf);
    head2_kernel<<<16, 256, 0, stream>>>(f1buf, fw2, fb2, fw3, fb3, tmat);
    out_kernel<<<256, 256, 0, stream>>>(x, tmat, out);
}

// Round 12
// 448.290 us; speedup vs baseline: 1.0602x; 1.0602x over previous
//
#include <hip/hip_runtime.h>
#include <hip/hip_fp8.h>

typedef __bf16 bf16_t;
typedef __bf16 bf16x8 __attribute__((ext_vector_type(8)));
typedef float floatx16 __attribute__((ext_vector_type(16)));
typedef int intx8 __attribute__((ext_vector_type(8)));
typedef unsigned long long u64;

#define B_ 16
#define N_ 4096
#define K_ 32

// ws layout (bytes):
//   idx   u16 [16][4096][32]         @ 0        (4194304)
//   g_enc u32 [16][1024]             @ 4194304  (65536)
//   w3f8  fp8 lane-contig [131072]   @ 4259840  (131072)   (= w3 * 16)
//   w2sw  bf16 frag-major [8192]     @ 4390912  (16384)    (K-axis permuted)
//   tmat  f32 [16][9]                @ 4407296  (576)
//   f1buf f32 [16][512]              @ 4407872  (32768)

__device__ __forceinline__ unsigned enc_f(float f) {
    unsigned u = __float_as_uint(f);
    return (u & 0x80000000u) ? ~u : (u | 0x80000000u);
}
__device__ __forceinline__ float dec_f(unsigned e) {
    return __uint_as_float((e & 0x80000000u) ? (e & 0x7fffffffu) : ~e);
}

__device__ __forceinline__ float max3f(float a, float b, float c) {
    float d;
    asm("v_max3_f32 %0, %1, %2, %3" : "=v"(d) : "v"(a), "v"(b), "v"(c));
    return d;
}

// compare-exchange: a <- min, b <- max (v_min_u32 / v_max_u32)
__device__ __forceinline__ void ce(unsigned& a, unsigned& b) {
    const unsigned mn = a < b ? a : b;
    const unsigned mx = a < b ? b : a;
    a = mn; b = mx;
}

// Batcher odd-even sort of 8 (ascending), 19 CE
__device__ __forceinline__ void sort8(unsigned* k) {
    ce(k[0], k[1]); ce(k[2], k[3]); ce(k[4], k[5]); ce(k[6], k[7]);
    ce(k[0], k[2]); ce(k[1], k[3]); ce(k[4], k[6]); ce(k[5], k[7]);
    ce(k[1], k[2]); ce(k[5], k[6]);
    ce(k[0], k[4]); ce(k[1], k[5]); ce(k[2], k[6]); ce(k[3], k[7]);
    ce(k[2], k[4]); ce(k[3], k[5]);
    ce(k[1], k[2]); ce(k[3], k[4]); ce(k[5], k[6]);
}
// keep lowest 8 of r ∪ k (both ascending) -> r ascending
__device__ __forceinline__ void merge_top8(unsigned* r, const unsigned* k) {
    unsigned s[8];
    #pragma unroll
    for (int u = 0; u < 8; u++)
        s[u] = r[u] < k[7 - u] ? r[u] : k[7 - u];
    ce(s[0], s[4]); ce(s[1], s[5]); ce(s[2], s[6]); ce(s[3], s[7]);
    ce(s[0], s[2]); ce(s[1], s[3]); ce(s[4], s[6]); ce(s[5], s[7]);
    ce(s[0], s[1]); ce(s[2], s[3]); ce(s[4], s[5]); ce(s[6], s[7]);
    #pragma unroll
    for (int u = 0; u < 8; u++) r[u] = s[u];
}

// ---------------------------------------------------------------------------
// K1: kNN top-32.  Round-12 changes (counter-driven, r11 profile:
// VALUBusy 77 / Occ 36 / 9.76M LDS bank conflicts):
//  (1) TWO-PASS scan over 2048-cand halves -> LDS 66KB -> 35.3KB, and
//      __launch_bounds__(512,8) -> 4 blocks/CU (was 2).  Scan keeps the
//      round-10 16-cand tournament; each thread now scans two 128-chunks.
//  (2) m1 merge scratch padded to STRIDE 33 dwords: kills the 32-way
//      write conflict (bank was k%32 for all 128 lanes) and the bank-
//      degenerate L2 head reads (now (4*tid+j)%32, 2-way = free).
// grid 2048 x 512.  Side jobs unchanged.
// LDS: cand float4[8*257]=32896B during passes; lists(18432B)+m1(16896B)
// = 35328B after (union 35328B).
// ---------------------------------------------------------------------------
__global__ __launch_bounds__(512, 8) void knn_kernel(
    const float* __restrict__ x, const float* __restrict__ w3,
    const float* __restrict__ w2, unsigned short* __restrict__ idxb,
    unsigned* __restrict__ g_enc, unsigned char* __restrict__ w3f8,
    bf16_t* __restrict__ w2sw)
{
    __shared__ __align__(16) unsigned smem_u[8832];   // 35328 B
    float4* cand = (float4*)smem_u;                   // 8*257 float4
    unsigned* lists = smem_u;                         // 512*9 dwords
    unsigned* m1 = smem_u + 4608;                     // 128 lists * 33 dwords
    const int tid = threadIdx.x;
    const int bid = blockIdx.x;  // 2048 blocks

    {
        const int g = bid * 512 + tid;
        if (g < 131072) {
            const int j  = g & 31;
            const int lI = (g >> 5) & 63;
            const int kq = (g >> 11) & 1;
            const int cb = g >> 12;
            const int mt2 = kq * 2 + (j >> 4), q = j & 15;
            const int lmI = lI & 31, hiI = lI >> 5;
            const int ch = mt2 * 32 + (q & 3) + 8 * (q >> 2) + 4 * hiI;
            __hip_fp8_e4m3 t(16.0f * w3[(cb * 32 + lmI) * 128 + ch]);
            w3f8[g] = t.__x;
        } else if (g < 139264) {
            const int o = g - 131072;
            const int f = o >> 9, r = o & 511, lI = r >> 3, jj = r & 7;
            const int ks = f & 3, nb = f >> 2, lmI = lI & 31, hiI = lI >> 5;
            const int ic = ks * 16 + 4 * hiI + 8 * (jj >> 2) + (jj & 3);
            w2sw[o] = (bf16_t)w2[(nb * 32 + lmI) * 64 + ic];
        } else if (g < 155648) {
            g_enc[g - 139264] = 0u;
        }
    }

    const int b  = bid >> 7;                    // 128 blocks per batch
    const int q  = tid >> 4;                    // local query 0..31
    const int n  = (bid & 127) * 32 + q;        // global query index
    const int t  = tid & 15;                    // candidate chunk
    const float* xb = x + b * 3 * N_;

    const float xi0 = xb[n], xi1 = xb[N_ + n], xi2 = xb[2 * N_ + n];
    const float xisq1 = fmaf(xi0, xi0, fmaf(xi1, xi1, xi2 * xi2)) + 1.0f;

    unsigned r[8];
    #pragma unroll
    for (int s = 0; s < 8; s++) r[s] = 0x7F7FFFFFu;   // FLT_MAX sentinel

    const int pb = t * 128 + (t >> 1);          // padded base (local idx)

    #pragma unroll 1
    for (int pass = 0; pass < 2; pass++) {
        __syncthreads();        // previous use of cand region complete
        for (int j = tid; j < 2048; j += 512) {
            const int jg = pass * 2048 + j;
            float cx = xb[jg], cy = xb[N_ + jg], cz = xb[2 * N_ + jg];
            cand[j + (j >> 8)] = make_float4(-2.f * cx, -2.f * cy, -2.f * cz,
                                             fmaf(cx, cx, fmaf(cy, cy, cz * cz)));
        }
        __syncthreads();

        const int j0 = pass * 2048 + t * 128;
        #pragma unroll 1
        for (int jb = 0; jb < 128; jb += 16) {
            unsigned ka[8], kb[8];
            #pragma unroll
            for (int u = 0; u < 8; u++) {
                const float4 c = cand[pb + jb + u];
                const float d = fmaf(c.z, xi2, fmaf(c.y, xi1, fmaf(c.x, xi0, c.w)));
                ka[u] = (__float_as_uint(d + xisq1) & 0xFFFFF000u)
                      | (unsigned)(j0 + jb + u);
            }
            #pragma unroll
            for (int u = 0; u < 8; u++) {
                const float4 c = cand[pb + jb + 8 + u];
                const float d = fmaf(c.z, xi2, fmaf(c.y, xi1, fmaf(c.x, xi0, c.w)));
                kb[u] = (__float_as_uint(d + xisq1) & 0xFFFFF000u)
                      | (unsigned)(j0 + jb + 8 + u);
            }
            sort8(ka);
            sort8(kb);
            merge_top8(ka, kb);      // ka = sorted lowest-8 of the 16
            merge_top8(r, ka);       // fold into running top-8
        }
    }
    __syncthreads();      // scans done before lists overwrite cand

    #pragma unroll
    for (int k = 0; k < 8; k++) lists[tid * 9 + k] = r[k];
    __syncthreads();

    // L1: 4-way merge of sorted-8 lists -> m1 (stride-33 lists)
    if (tid < 128) {
        const int q1 = tid >> 2, gi = tid & 3;
        const int base = (q1 * 16 + gi * 4) * 9;
        unsigned h0 = lists[base], h1 = lists[base + 9];
        unsigned h2 = lists[base + 18], h3 = lists[base + 27];
        int p0 = 0, p1 = 0, p2 = 0, p3 = 0;
        unsigned* outp = m1 + (q1 * 4 + gi) * 33;
        #pragma unroll 1
        for (int k = 0; k < 32; k++) {
            const unsigned m01 = h0 < h1 ? h0 : h1;
            const unsigned m23 = h2 < h3 ? h2 : h3;
            const unsigned v = m01 < m23 ? m01 : m23;
            outp[k] = v;
            if (m01 < m23) {
                if (h1 < h0) { p1++; h1 = p1 < 8 ? lists[base + 9 + p1] : 0xFFFFFFFFu; }
                else         { p0++; h0 = p0 < 8 ? lists[base + p0]     : 0xFFFFFFFFu; }
            } else {
                if (h3 < h2) { p3++; h3 = p3 < 8 ? lists[base + 27 + p3] : 0xFFFFFFFFu; }
                else         { p2++; h2 = p2 < 8 ? lists[base + 18 + p2] : 0xFFFFFFFFu; }
            }
        }
    }
    __syncthreads();

    // L2: 4-way merge of the four stride-33 lists -> top-32 -> idxb
    if (tid < 32) {
        const unsigned* l0 = m1 + (tid * 4 + 0) * 33;
        const unsigned* l1 = m1 + (tid * 4 + 1) * 33;
        const unsigned* l2 = m1 + (tid * 4 + 2) * 33;
        const unsigned* l3 = m1 + (tid * 4 + 3) * 33;
        unsigned h0 = l0[0], h1 = l1[0], h2 = l2[0], h3 = l3[0];
        int p0 = 0, p1 = 0, p2 = 0, p3 = 0;
        const int nq = (bid & 127) * 32 + tid;
        unsigned short* op = idxb + ((size_t)(b * N_ + nq)) * K_;
        #pragma unroll 1
        for (int k = 0; k < K_; k++) {
            const unsigned m01 = h0 < h1 ? h0 : h1;
            const unsigned m23 = h2 < h3 ? h2 : h3;
            const unsigned v = m01 < m23 ? m01 : m23;
            op[k] = (unsigned short)(v & 0xFFFu);
            if (m01 < m23) {
                if (h1 < h0) { p1++; h1 = p1 < 32 ? l1[p1] : 0xFFFFFFFFu; }
                else         { p0++; h0 = p0 < 32 ? l0[p0] : 0xFFFFFFFFu; }
            } else {
                if (h3 < h2) { p3++; h3 = p3 < 32 ? l3[p3] : 0xFFFFFFFFu; }
                else         { p2++; h2 = p2 < 32 ? l2[p2] : 0xFFFFFFFFu; }
            }
        }
    }
}

// epilogue for one finished layer-3 chunk: max-reduce 32 values via v_max3
// chains and LDS atomicMax (both half-wave lanes hit the same slot).
__device__ __forceinline__ void chunk_epilogue(
    const floatx16& a0, const floatx16& a1, int cb, unsigned* gl, int lm)
{
    float c0 = fmaxf(a0[0], a1[0]);
    float c1 = fmaxf(a0[1], a1[1]);
    float c2 = fmaxf(a0[2], a1[2]);
    float c3 = fmaxf(a0[3], a1[3]);
    #pragma unroll
    for (int o = 4; o < 16; o += 4) {
        c0 = max3f(a0[o + 0], a1[o + 0], c0);
        c1 = max3f(a0[o + 1], a1[o + 1], c1);
        c2 = max3f(a0[o + 2], a1[o + 2], c2);
        c3 = max3f(a0[o + 3], a1[o + 3], c3);
    }
    const float m = max3f(c0, c1, fmaxf(c2, c3));
    atomicMax(&gl[cb * 32 + lm], enc_f(m));
}

// ---------------------------------------------------------------------------
// K2: fused edge MLP — round-5 verified body, single dispatch (grid 8192).
// ---------------------------------------------------------------------------
__global__ __launch_bounds__(256, 3) void mlp_kernel(
    const float* __restrict__ x, const unsigned short* __restrict__ idxb,
    const float* __restrict__ w1, const float* __restrict__ b1,
    const float* __restrict__ b2,
    const bf16_t* __restrict__ w2sw, const unsigned char* __restrict__ w3f8,
    unsigned* __restrict__ g_enc)
{
    __shared__ unsigned gl[1024];                 // 4096 B
    __shared__ __align__(16) float4 w1l[64];      // 1024 B
    __shared__ __align__(16) float b2s[128];      // 512 B  (= 256*b2)

    const int tid = threadIdx.x;
    const int b   = blockIdx.x >> 9;          // 512 blocks per batch
    const int p0  = (blockIdx.x & 511) * 8;   // first point
    const float* xb = x + b * 3 * N_;

    const int wv = tid >> 6;
    const int l  = tid & 63;
    const int lm = l & 31;
    const int hi = l >> 5;

    for (int i = tid; i < 1024; i += 256) gl[i] = 0u;
    if (tid < 64)
        w1l[tid] = make_float4(w1[tid * 3], w1[tid * 3 + 1], w1[tid * 3 + 2], b1[tid]);
    else if (tid < 192)
        b2s[tid - 64] = 256.0f * b2[tid - 64];
    __syncthreads();

    const floatx16 zf = (floatx16)0.f;   // hoisted zero C-input

    const unsigned char* w3p = w3f8 + l * 32;
#define PREFETCH_W3(dst, c) do {                                              \
        dst[0] = *(const intx8*)(w3p + (c) * 4096);                           \
        dst[1] = *(const intx8*)(w3p + (c) * 4096 + 2048);                    \
    } while (0)

    intx8 bwA[2], bwB[2];
    PREFETCH_W3(bwA, 0);     // in flight during layers 1+2

    // ---- edge gathers ----
    float d0[2], d1[2], d2[2];
    #pragma unroll
    for (int nt2 = 0; nt2 < 2; nt2++) {
        const int pp = p0 + wv * 2 + nt2;                // wave-uniform point
        const int j  = idxb[((size_t)(b * N_ + pp)) * K_ + lm];
        d0[nt2] = xb[j]          - xb[pp];
        d1[nt2] = xb[N_ + j]     - xb[N_ + pp];
        d2[nt2] = xb[2 * N_ + j] - xb[2 * N_ + pp];
    }

    // ---- layer 1 via MFMA (K=4, bias in k=3) ----
    bf16x8 a1f[2];                       // A: (w1|b1) per 32-ch tile, hi=0 only
    #pragma unroll
    for (int tt = 0; tt < 2; tt++) {
        const float4 w = w1l[tt * 32 + lm];
        bf16x8 v = (bf16x8)(bf16_t)0.f;
        if (hi == 0) {
            v[0] = (bf16_t)w.x; v[1] = (bf16_t)w.y;
            v[2] = (bf16_t)w.z; v[3] = (bf16_t)w.w;
        }
        a1f[tt] = v;
    }

    bf16x8 b1h[2][4];   // [nt2][ks]; layer-2 B-frags
    #pragma unroll
    for (int nt2 = 0; nt2 < 2; nt2++) {
        bf16x8 bf = (bf16x8)(bf16_t)0.f;   // B: (d0,d1,d2,1), hi=0 only
        if (hi == 0) {
            bf[0] = (bf16_t)d0[nt2]; bf[1] = (bf16_t)d1[nt2];
            bf[2] = (bf16_t)d2[nt2]; bf[3] = (bf16_t)1.0f;
        }
        floatx16 hacc[2];
        hacc[0] = __builtin_amdgcn_mfma_f32_32x32x16_bf16(a1f[0], bf, zf, 0, 0, 0);
        hacc[1] = __builtin_amdgcn_mfma_f32_32x32x16_bf16(a1f[1], bf, zf, 0, 0, 0);
        #pragma unroll
        for (int ks = 0; ks < 4; ks++)
            #pragma unroll
            for (int jj = 0; jj < 8; jj++)
                b1h[nt2][ks][jj] = (bf16_t)fmaxf(
                    hacc[ks >> 1][(jj & 3) + 4 * (jj >> 2) + 8 * (ks & 1)], 0.f);
    }

    // ---- layer 2 (MFMA 32x32x16 bf16, transposed) + fused fp8 pack -> a3v ----
    intx8 a3v[2][2];   // [nt2 = edge m-tile][kq]; byte map matches w3f8
    #pragma unroll
    for (int mt2 = 0; mt2 < 4; mt2++) {          // channel tile (M side)
        floatx16 acc0 = (floatx16)0.f, acc1 = (floatx16)0.f;
        #pragma unroll
        for (int ks = 0; ks < 4; ks++) {
            const bf16x8 aw = *(const bf16x8*)&w2sw[((mt2 * 4 + ks) * 64 + l) * 8];
            acc0 = __builtin_amdgcn_mfma_f32_32x32x16_bf16(aw, b1h[0][ks], acc0, 0, 0, 0);
            acc1 = __builtin_amdgcn_mfma_f32_32x32x16_bf16(aw, b1h[1][ks], acc1, 0, 0, 0);
        }
        const int kq = mt2 >> 1, c0 = (mt2 & 1) * 4;
        #pragma unroll
        for (int i2 = 0; i2 < 4; i2++) {
            // channels mt2*32 + 8*i2 + 4*hi + {0..3}  (lane-uniform per hi)
            const float4 bb = *(const float4*)&b2s[mt2 * 32 + i2 * 8 + hi * 4];
            {
                const float v0 = fmaxf(fmaf(acc0[4 * i2 + 0], 256.f, bb.x), 0.f);
                const float v1 = fmaxf(fmaf(acc0[4 * i2 + 1], 256.f, bb.y), 0.f);
                const float v2 = fmaxf(fmaf(acc0[4 * i2 + 2], 256.f, bb.z), 0.f);
                const float v3 = fmaxf(fmaf(acc0[4 * i2 + 3], 256.f, bb.w), 0.f);
                int w = __builtin_amdgcn_cvt_pk_fp8_f32(v0, v1, 0, false);
                w = __builtin_amdgcn_cvt_pk_fp8_f32(v2, v3, w, true);
                a3v[0][kq][c0 + i2] = w;
            }
            {
                const float v0 = fmaxf(fmaf(acc1[4 * i2 + 0], 256.f, bb.x), 0.f);
                const float v1 = fmaxf(fmaf(acc1[4 * i2 + 1], 256.f, bb.y), 0.f);
                const float v2 = fmaxf(fmaf(acc1[4 * i2 + 2], 256.f, bb.z), 0.f);
                const float v3 = fmaxf(fmaf(acc1[4 * i2 + 3], 256.f, bb.w), 0.f);
                int w = __builtin_amdgcn_cvt_pk_fp8_f32(v0, v1, 0, false);
                w = __builtin_amdgcn_cvt_pk_fp8_f32(v2, v3, w, true);
                a3v[1][kq][c0 + i2] = w;
            }
        }
    }

    // ---- layer 3: 32 chunks of 32 out-channels; scaled fp8 MFMA (K=64),
    //      pairwise double-pipeline: MFMA of chunk c || epilogue of c-1 ----
#define COMPUTE_W3(d0_, d1_, buf) do {                                        \
        __builtin_amdgcn_s_setprio(1);                                        \
        d0_ = __builtin_amdgcn_mfma_scale_f32_32x32x64_f8f6f4(                \
            a3v[0][0], buf[0], zf, 0, 0, 0, 0x7F7F7F7F, 0, 0x7F7F7F7F);       \
        d1_ = __builtin_amdgcn_mfma_scale_f32_32x32x64_f8f6f4(                \
            a3v[1][0], buf[0], zf, 0, 0, 0, 0x7F7F7F7F, 0, 0x7F7F7F7F);       \
        d0_ = __builtin_amdgcn_mfma_scale_f32_32x32x64_f8f6f4(                \
            a3v[0][1], buf[1], d0_, 0, 0, 0, 0x7F7F7F7F, 0, 0x7F7F7F7F);      \
        d1_ = __builtin_amdgcn_mfma_scale_f32_32x32x64_f8f6f4(                \
            a3v[1][1], buf[1], d1_, 0, 0, 0, 0x7F7F7F7F, 0, 0x7F7F7F7F);      \
        __builtin_amdgcn_s_setprio(0); } while (0)

    floatx16 pA0, pA1, pB0, pB1;

    PREFETCH_W3(bwB, 1);
    COMPUTE_W3(pA0, pA1, bwA);          // chunk 0

    #pragma unroll 1
    for (int cc = 0; cc < 15; cc++) {
        PREFETCH_W3(bwA, 2 * cc + 2);
        COMPUTE_W3(pB0, pB1, bwB);      // chunk 2cc+1
        chunk_epilogue(pA0, pA1, 2 * cc, gl, lm);
        PREFETCH_W3(bwB, 2 * cc + 3);
        COMPUTE_W3(pA0, pA1, bwA);      // chunk 2cc+2
        chunk_epilogue(pB0, pB1, 2 * cc + 1, gl, lm);
    }
    COMPUTE_W3(pB0, pB1, bwB);          // chunk 31
    chunk_epilogue(pA0, pA1, 30, gl, lm);
    chunk_epilogue(pB0, pB1, 31, gl, lm);

#undef PREFETCH_W3
#undef COMPUTE_W3

    __syncthreads();
    for (int i = tid; i < 1024; i += 256)
        atomicMax(&g_enc[b * 1024 + i], gl[i]);
}

// ---------------------------------------------------------------------------
// K3a: FC head layer 1, split across 128 blocks (8 per batch) so the 2 MB
// fw1 read spreads over 128 CUs.  4 threads/output, LDS reduce.
// ---------------------------------------------------------------------------
__global__ __launch_bounds__(256) void head1_kernel(
    const unsigned* __restrict__ g_enc, const float* __restrict__ b3,
    const float* __restrict__ fw1, const float* __restrict__ fb1,
    float* __restrict__ f1buf)
{
    __shared__ __align__(16) float g[1024];
    __shared__ float red[256];
    const int t = threadIdx.x;
    const int b = blockIdx.x >> 3;       // batch
    const int s = blockIdx.x & 7;        // output slice (64 outs)

    for (int i = t; i < 1024; i += 256)
        g[i] = fmaxf(fmaf(dec_f(g_enc[b * 1024 + i]), 2.44140625e-4f, b3[i]), 0.f);
    __syncthreads();

    const int o = s * 64 + (t & 63);
    const int quarter = t >> 6;
    const float4* wr = (const float4*)(fw1 + (size_t)o * 1024) + quarter * 64;
    const float4* gv = (const float4*)g + quarter * 64;
    float acc = 0.f;
    #pragma unroll 4
    for (int i = 0; i < 64; i++) {
        float4 a = wr[i], c = gv[i];
        acc = fmaf(a.x, c.x, acc); acc = fmaf(a.y, c.y, acc);
        acc = fmaf(a.z, c.z, acc); acc = fmaf(a.w, c.w, acc);
    }
    red[t] = acc;
    __syncthreads();
    if (t < 64) {
        const float v = red[t] + red[t + 64] + red[t + 128] + red[t + 192];
        f1buf[b * 512 + s * 64 + t] = fmaxf(v + fb1[s * 64 + t], 0.f);
    }
}

// ---------------------------------------------------------------------------
// K3b: FC head layers 2+3. grid 16 x 256.
// ---------------------------------------------------------------------------
__global__ __launch_bounds__(256) void head2_kernel(
    const float* __restrict__ f1buf,
    const float* __restrict__ fw2, const float* __restrict__ fb2,
    const float* __restrict__ fw3, const float* __restrict__ fb3,
    float* __restrict__ tmat)
{
    __shared__ __align__(16) float f1[512];
    __shared__ __align__(16) float f2[256];
    const int t = threadIdx.x, b = blockIdx.x;

    if (t < 128) ((float4*)f1)[t] = ((const float4*)(f1buf + b * 512))[t];
    __syncthreads();
    {
        const int o = t;
        const float4* wr = (const float4*)(fw2 + (size_t)o * 512);
        const float4* fv = (const float4*)f1;
        float acc = fb2[o];
        for (int i = 0; i < 128; i++) {
            float4 a = wr[i], c = fv[i];
            acc = fmaf(a.x, c.x, acc); acc = fmaf(a.y, c.y, acc);
            acc = fmaf(a.z, c.z, acc); acc = fmaf(a.w, c.w, acc);
        }
        f2[o] = fmaxf(acc, 0.f);
    }
    __syncthreads();
    if (t < 9) {
        const float4* wr = (const float4*)(fw3 + (size_t)t * 256);
        const float4* fv = (const float4*)f2;
        float acc = fb3[t];
        for (int i = 0; i < 64; i++) {
            float4 a = wr[i], c = fv[i];
            acc = fmaf(a.x, c.x, acc); acc = fmaf(a.y, c.y, acc);
            acc = fmaf(a.z, c.z, acc); acc = fmaf(a.w, c.w, acc);
        }
        if (t == 0 || t == 4 || t == 8) acc += 1.f;
        tmat[b * 9 + t] = acc;
    }
}

// ---------------------------------------------------------------------------
// K4: out[b][d][n] = sum_c x[b][c][n] * t[b][c][d].  grid 256 x 256.
// ---------------------------------------------------------------------------
__global__ __launch_bounds__(256) void out_kernel(
    const float* __restrict__ x, const float* __restrict__ tmat,
    float* __restrict__ out)
{
    const int gid = blockIdx.x * 256 + threadIdx.x;
    const int b = gid >> 12, n = gid & 4095;
    const float* T = tmat + b * 9;
    const float x0 = x[b * 12288 + n];
    const float x1 = x[b * 12288 + 4096 + n];
    const float x2 = x[b * 12288 + 8192 + n];
    #pragma unroll
    for (int d = 0; d < 3; d++)
        out[b * 12288 + d * 4096 + n] =
            fmaf(x2, T[6 + d], fmaf(x1, T[3 + d], x0 * T[d]));
}

extern "C" void kernel_launch(void* const* d_in, const int* in_sizes, int n_in,
                              void* d_out, int out_size, void* d_ws, size_t ws_size,
                              hipStream_t stream) {
    const float* x   = (const float*)d_in[0];
    const float* w1  = (const float*)d_in[1];
    const float* b1  = (const float*)d_in[2];
    const float* w2  = (const float*)d_in[3];
    const float* b2  = (const float*)d_in[4];
    const float* w3  = (const float*)d_in[5];
    const float* b3  = (const float*)d_in[6];
    const float* fw1 = (const float*)d_in[7];
    const float* fb1 = (const float*)d_in[8];
    const float* fw2 = (const float*)d_in[9];
    const float* fb2 = (const float*)d_in[10];
    const float* fw3 = (const float*)d_in[11];
    const float* fb3 = (const float*)d_in[12];
    float* out = (float*)d_out;

    char* ws = (char*)d_ws;
    unsigned short* idxb = (unsigned short*)ws;
    unsigned* g_enc = (unsigned*)(ws + 4194304);
    unsigned char* w3f8 = (unsigned char*)(ws + 4259840);
    bf16_t* w2sw = (bf16_t*)(ws + 4390912);
    float* tmat  = (float*)(ws + 4407296);
    float* f1buf = (float*)(ws + 4407872);

    knn_kernel<<<2048, 512, 0, stream>>>(x, w3, w2, idxb, g_enc, w3f8, w2sw);
    mlp_kernel<<<8192, 256, 0, stream>>>(x, idxb, w1, b1, b2, w2sw, w3f8, g_enc);
    head1_kernel<<<128, 256, 0, stream>>>(g_enc, b3, fw1, fb1, f1buf);
    head2_kernel<<<16, 256, 0, stream>>>(f1buf, fw2, fb2, fw3, fb3, tmat);
    out_kernel<<<256, 256, 0, stream>>>(x, tmat, out);
}